// Round 2
// baseline (548.947 us; speedup 1.0000x reference)
//
#include <hip/hip_runtime.h>

// Problem constants
#define LROW 32768                    // row length
#define NROW 512                      // rows
#define WIN 100                       // window (34*3-2)
#define NC (LROW - WIN + 1)           // 32669 output columns
#define NTHREADS 128                  // 2 waves / block
#define T 32                          // columns per thread (sliding window)
#define CT (T * NTHREADS)             // 4096 columns per block
#define NTILE ((NC + CT - 1) / CT)    // 8 column tiles
#define G 4                           // rows per block
#define RG (NROW / G)                 // 128 row groups
#define SEG (CT + WIN - 1)            // 4195 staged elements per row-channel
#define SEGP (SEG + (SEG >> 5) + 1)   // padded LDS capacity (pad 1 word per 32)

__device__ __forceinline__ int padidx(int e) { return e + (e >> 5); }

// PASS2=0: accumulate per-column corr sums into colsum (atomics).
// PASS2=1: recompute corr, subtract avg=colsum/512, relu, store.
template <int PASS2>
__global__ __launch_bounds__(NTHREADS, 2)
void swc_kernel(const float* __restrict__ x, float* __restrict__ colsum,
                float* __restrict__ out)
{
    __shared__ float lds1[SEGP];   // channel 0 segment (bank-padded)
    __shared__ float lds2[SEGP];   // channel 1 segment (bank-padded)

    const int tile = (int)blockIdx.x / RG;
    const int rg   = (int)blockIdx.x % RG;
    const int j0   = tile * CT;
    const int seglen = min(SEG, LROW - j0);
    const int ncols  = min(CT, NC - j0);     // valid columns in this tile
    const int c0   = (int)threadIdx.x * T;   // multiple of 32
    const int pbase = c0 + (c0 >> 5);        // padded base index
    const bool active = c0 < ncols;

    float acc[T];
    float ravg[T];
    if (PASS2) {
        #pragma unroll
        for (int m = 0; m < T; ++m) {
            int j = j0 + c0 + m;
            ravg[m] = (j < NC) ? colsum[j] * (1.0f / (float)NROW) : 0.0f;
        }
    } else {
        #pragma unroll
        for (int m = 0; m < T; ++m) acc[m] = 0.0f;
    }

    const int r0 = rg * G;
    for (int r = r0; r < r0 + G; ++r) {
        const float* __restrict__ p1 = x + ((size_t)(2 * r) + 0) * LROW + j0;
        const float* __restrict__ p2 = x + ((size_t)(2 * r) + 1) * LROW + j0;
        __syncthreads();   // prior iteration's LDS readers done
        // ---- stage segment into padded LDS (float4 global loads) ----
        const int nvec = seglen >> 2;
        for (int i = (int)threadIdx.x; i < nvec; i += NTHREADS) {
            float4 v1 = ((const float4*)p1)[i];
            float4 v2 = ((const float4*)p2)[i];
            int b = padidx(4 * i);   // 4-group never crosses a pad boundary
            lds1[b + 0] = v1.x; lds1[b + 1] = v1.y; lds1[b + 2] = v1.z; lds1[b + 3] = v1.w;
            lds2[b + 0] = v2.x; lds2[b + 1] = v2.y; lds2[b + 2] = v2.z; lds2[b + 3] = v2.w;
        }
        for (int e = (nvec << 2) + (int)threadIdx.x; e < seglen; e += NTHREADS) {
            lds1[padidx(e)] = p1[e];
            lds2[padidx(e)] = p2[e];
        }
        __syncthreads();

        float rout[T];
        if (active) {
            float s1 = 0.f, s2 = 0.f, s11 = 0.f, s22 = 0.f, s12 = 0.f;
            #pragma unroll
            for (int k = 0; k < WIN; ++k) {      // compile-time padded offsets
                float a = lds1[pbase + k + (k >> 5)];
                float b = lds2[pbase + k + (k >> 5)];
                s1 += a; s2 += b;
                s11 = fmaf(a, a, s11);
                s22 = fmaf(b, b, s22);
                s12 = fmaf(a, b, s12);
            }
            #pragma unroll
            for (int m = 0; m < T; ++m) {
                if (m > 0) {
                    const int eo = m - 1, ei = m - 1 + WIN;
                    float a_o = lds1[pbase + eo + (eo >> 5)];
                    float b_o = lds2[pbase + eo + (eo >> 5)];
                    float a_i = lds1[pbase + ei + (ei >> 5)];
                    float b_i = lds2[pbase + ei + (ei >> 5)];
                    s1 += a_i - a_o;
                    s2 += b_i - b_o;
                    s11 += fmaf(a_i, a_i, -(a_o * a_o));
                    s22 += fmaf(b_i, b_i, -(b_o * b_o));
                    s12 += fmaf(a_i, b_i, -(a_o * b_o));
                }
                if (c0 + m < ncols) {
                    const float invw = 1.0f / (float)WIN;
                    float cov = fmaf(-(s1 * invw), s2, s12);
                    float v1v = fmaf(-(s1 * invw), s1, s11);
                    float v2v = fmaf(-(s2 * invw), s2, s22);
                    float corr = cov * rsqrtf(v1v * v2v);
                    if (PASS2) rout[m] = corr - ravg[m];
                    else       acc[m] += corr;
                } else if (PASS2) {
                    rout[m] = 0.0f;
                }
            }
        } else if (PASS2) {
            #pragma unroll
            for (int m = 0; m < T; ++m) rout[m] = 0.0f;
        }

        if (PASS2) {
            __syncthreads();   // all compute reads of lds1/lds2 done
            #pragma unroll
            for (int m = 0; m < T; ++m) lds1[pbase + m] = rout[m];  // stage (2-way, free)
            __syncthreads();
            float* __restrict__ orow = out + (size_t)r * NC + j0;
            for (int e = (int)threadIdx.x; e < ncols; e += NTHREADS) {
                float v = lds1[padidx(e)];
                orow[e] = fmaxf(v, 0.0f);   // lane-contiguous coalesced stores
            }
        }
    }

    if (!PASS2 && active) {
        #pragma unroll
        for (int m = 0; m < T; ++m) {
            if (c0 + m < ncols) atomicAdd(&colsum[j0 + c0 + m], acc[m]);
        }
    }
}

extern "C" void kernel_launch(void* const* d_in, const int* in_sizes, int n_in,
                              void* d_out, int out_size, void* d_ws, size_t ws_size,
                              hipStream_t stream) {
    const float* x = (const float*)d_in[0];
    float* out = (float*)d_out;
    float* colsum = (float*)d_ws;   // NC floats = ~131 KB scratch

    hipMemsetAsync(colsum, 0, NC * sizeof(float), stream);
    swc_kernel<0><<<dim3(NTILE * RG), dim3(NTHREADS), 0, stream>>>(x, colsum, out);
    swc_kernel<1><<<dim3(NTILE * RG), dim3(NTHREADS), 0, stream>>>(x, colsum, out);
}

// Round 3
// 311.659 us; speedup vs baseline: 1.7614x; 1.7614x over previous
//
#include <hip/hip_runtime.h>

// Problem constants
#define LROW 32768                    // row length
#define NROW 512                      // rows
#define WIN 100                       // window (34*3-2)
#define NC (LROW - WIN + 1)           // 32669 output columns
#define NT1 256                       // 4 waves / block (pass 1)
#define T 8                           // columns per thread (small => no reg-array spills)
#define CT (T * NT1)                  // 2048 columns per block
#define NTILE ((NC + CT - 1) / CT)    // 16 column tiles
#define G 4                           // rows per block
#define RG (NROW / G)                 // 128 row groups
#define SEG (CT + WIN - 1)            // 2147 staged elements per channel
#define SEGP (SEG + (SEG >> 3) + 2)   // pad 1 word per 8 elements

__device__ __forceinline__ int pad8(int e) { return e + (e >> 3); }

// Pass 1: compute corr, write corr to out, accumulate column sums (atomics).
__global__ __launch_bounds__(NT1, 4)
void swc_pass1(const float* __restrict__ x, float* __restrict__ colsum,
               float* __restrict__ out)
{
    __shared__ float lds1[SEGP];   // channel 0 segment (pad-8)
    __shared__ float lds2[SEGP];   // channel 1 segment (pad-8)

    const int tile = (int)blockIdx.x % NTILE;
    const int rg   = (int)blockIdx.x / NTILE;
    const int j0   = tile * CT;
    const int seglen = min(SEG, LROW - j0);
    const int ncols  = min(CT, NC - j0);
    const int tid  = (int)threadIdx.x;
    const int c0   = tid * T;              // multiple of 8
    const int pbase = 9 * tid;             // pad8(c0) since c0 = 8*tid
    const bool active = c0 < ncols;

    float acc[T];
    #pragma unroll
    for (int m = 0; m < T; ++m) acc[m] = 0.0f;

    const int r0 = rg * G;
    for (int r = r0; r < r0 + G; ++r) {
        const float* __restrict__ p1 = x + ((size_t)(2 * r) + 0) * LROW + j0;
        const float* __restrict__ p2 = x + ((size_t)(2 * r) + 1) * LROW + j0;
        __syncthreads();   // prior iteration's LDS readers done
        // ---- stage segment into pad-8 LDS (float4 global loads) ----
        const int nvec = seglen >> 2;
        for (int i = tid; i < nvec; i += NT1) {       // 2-3 iterations
            float4 v1 = ((const float4*)p1)[i];
            float4 v2 = ((const float4*)p2)[i];
            int b = 4 * i + (i >> 1);                 // pad8(4i); 4-group stays in one octet
            lds1[b + 0] = v1.x; lds1[b + 1] = v1.y; lds1[b + 2] = v1.z; lds1[b + 3] = v1.w;
            lds2[b + 0] = v2.x; lds2[b + 1] = v2.y; lds2[b + 2] = v2.z; lds2[b + 3] = v2.w;
        }
        for (int e = (nvec << 2) + tid; e < seglen; e += NT1) {
            lds1[pad8(e)] = p1[e];
            lds2[pad8(e)] = p2[e];
        }
        __syncthreads();

        float rout[T];
        if (active) {
            float s1 = 0.f, s2 = 0.f, s11 = 0.f, s22 = 0.f, s12 = 0.f;
            #pragma unroll
            for (int k = 0; k < WIN; ++k) {           // compile-time pad offsets
                float a = lds1[pbase + k + (k >> 3)];
                float b = lds2[pbase + k + (k >> 3)];
                s1 += a; s2 += b;
                s11 = fmaf(a, a, s11);
                s22 = fmaf(b, b, s22);
                s12 = fmaf(a, b, s12);
            }
            #pragma unroll
            for (int m = 0; m < T; ++m) {
                if (m > 0) {
                    const int eo = m - 1, ei = m - 1 + WIN;
                    float a_o = lds1[pbase + eo];               // eo<8 -> no pad term
                    float b_o = lds2[pbase + eo];
                    float a_i = lds1[pbase + ei + (ei >> 3)];
                    float b_i = lds2[pbase + ei + (ei >> 3)];
                    s1 += a_i - a_o;
                    s2 += b_i - b_o;
                    s11 += fmaf(a_i, a_i, -(a_o * a_o));
                    s22 += fmaf(b_i, b_i, -(b_o * b_o));
                    s12 += fmaf(a_i, b_i, -(a_o * b_o));
                }
                const float invw = 1.0f / (float)WIN;
                float cov = fmaf(-(s1 * invw), s2, s12);
                float v1v = fmaf(-(s1 * invw), s1, s11);
                float v2v = fmaf(-(s2 * invw), s2, s22);
                float corr = cov * rsqrtf(v1v * v2v);
                rout[m] = corr;
                if (c0 + m < ncols) acc[m] += corr;
            }
        } else {
            #pragma unroll
            for (int m = 0; m < T; ++m) rout[m] = 0.0f;
        }

        __syncthreads();   // all compute reads of lds1/lds2 done
        #pragma unroll
        for (int m = 0; m < T; ++m) lds1[pbase + m] = rout[m];   // pad8(c0+m)=pbase+m
        __syncthreads();
        float* __restrict__ orow = out + (size_t)r * NC + j0;
        for (int e = tid; e < ncols; e += NT1) {
            orow[e] = lds1[pad8(e)];   // corr (pre-relu), coalesced dword stores
        }
    }

    if (active) {
        #pragma unroll
        for (int m = 0; m < T; ++m) {
            if (c0 + m < ncols) atomicAdd(&colsum[j0 + c0 + m], acc[m]);
        }
    }
}

// Pass 2: out = relu(out - colsum/NROW), pure streaming elementwise.
__global__ __launch_bounds__(256)
void swc_pass2(float* __restrict__ out, const float* __restrict__ colsum)
{
    const int row = (int)blockIdx.y;
    const int j0  = (int)blockIdx.x * 4096;
    float* __restrict__ orow = out + (size_t)row * NC;
    #pragma unroll
    for (int k = 0; k < 16; ++k) {
        int col = j0 + k * 256 + (int)threadIdx.x;
        if (col < NC) {
            float avg = colsum[col] * (1.0f / (float)NROW);
            float v = orow[col] - avg;
            orow[col] = fmaxf(v, 0.0f);
        }
    }
}

extern "C" void kernel_launch(void* const* d_in, const int* in_sizes, int n_in,
                              void* d_out, int out_size, void* d_ws, size_t ws_size,
                              hipStream_t stream) {
    const float* x = (const float*)d_in[0];
    float* out = (float*)d_out;
    float* colsum = (float*)d_ws;   // NC floats = ~131 KB scratch

    hipMemsetAsync(colsum, 0, NC * sizeof(float), stream);
    swc_pass1<<<dim3(NTILE * RG), dim3(NT1), 0, stream>>>(x, colsum, out);
    swc_pass2<<<dim3(8, NROW), dim3(256), 0, stream>>>(out, colsum);
}

// Round 6
// 296.124 us; speedup vs baseline: 1.8538x; 1.0525x over previous
//
#include <hip/hip_runtime.h>

// Problem constants
#define LROW 32768                     // row length
#define NROW 512                       // rows
#define WIN 100                        // window (34*3-2)
#define NC (LROW - WIN + 1)            // 32669 output columns
#define NT1 256                        // 4 waves / block (pass 1)
#define T 16                           // columns per thread
#define CT (T * NT1)                   // 4096 columns per block
#define NTILE ((NC + CT - 1) / CT)     // 8 column tiles
#define G 4                            // rows per block
#define RG (NROW / G)                  // 128 row groups
#define SEG (CT + WIN - 1)             // 4195 staged elements per channel
#define SEGP (SEG + 3 * (SEG >> 4) + 4)  // 4985: pad 3 words per 16 (stride 19/thread)
#define N_TOT (NROW * NC)              // 16,726,528
#define N4 (N_TOT / 4)                 // 4,181,632 (divisible by 4)
#define RSPLIT 32
#define RCHUNK (NROW / RSPLIT)         // 16 rows per reduce block

__device__ __forceinline__ int pad3(int e) { return e + 3 * (e >> 4); }

// Pass 1: compute corr for G rows x CT cols per block, store corr to out.
// Thread t owns cols [16t,16t+15]; LDS layout padded so thread base = 19t
// -> every compute read is (19*lane + const) mod 32 banks = 2 lanes/bank (free).
__global__ __launch_bounds__(NT1, 4)
void swc_pass1(const float* __restrict__ x, float* __restrict__ out)
{
    __shared__ float lds1[SEGP];
    __shared__ float lds2[SEGP];

    const int tile = (int)blockIdx.x % NTILE;
    const int rg   = (int)blockIdx.x / NTILE;
    const int j0   = tile * CT;
    const int seglen = min(SEG, LROW - j0);
    const int ncols  = min(CT, NC - j0);
    const int tid  = (int)threadIdx.x;
    const int c0   = tid * T;
    const int pbase = 19 * tid;        // pad3(16*tid)

    const int r0 = rg * G;
    for (int rr = 0; rr < G; ++rr) {
        const int r = r0 + rr;
        const float* __restrict__ p1 = x + ((size_t)(2 * r) + 0) * LROW + j0;
        const float* __restrict__ p2 = x + ((size_t)(2 * r) + 1) * LROW + j0;
        __syncthreads();   // prior iteration's LDS readers done
        // ---- stage segment into pad-16/3 LDS (float4 global loads) ----
        const int nvec = seglen >> 2;
        for (int i = tid; i < nvec; i += NT1) {
            float4 v1 = ((const float4*)p1)[i];
            float4 v2 = ((const float4*)p2)[i];
            int b = 4 * i + 3 * (i >> 2);     // pad3(4i); 4-group stays in one 16-group
            lds1[b + 0] = v1.x; lds1[b + 1] = v1.y; lds1[b + 2] = v1.z; lds1[b + 3] = v1.w;
            lds2[b + 0] = v2.x; lds2[b + 1] = v2.y; lds2[b + 2] = v2.z; lds2[b + 3] = v2.w;
        }
        for (int e = (nvec << 2) + tid; e < seglen; e += NT1) {
            lds1[pad3(e)] = p1[e];
            lds2[pad3(e)] = p2[e];
        }
        __syncthreads();

        // ---- window init (compile-time padded offsets) ----
        float s1 = 0.f, s2 = 0.f, s11 = 0.f, s22 = 0.f, s12 = 0.f;
        #pragma unroll
        for (int k = 0; k < WIN; ++k) {
            float a = lds1[pbase + k + 3 * (k >> 4)];
            float b = lds2[pbase + k + 3 * (k >> 4)];
            s1 += a; s2 += b;
            s11 = fmaf(a, a, s11);
            s22 = fmaf(b, b, s22);
            s12 = fmaf(a, b, s12);
        }
        // ---- slide across T columns, store corr directly ----
        float* __restrict__ orow = out + (size_t)r * NC + j0;
        #pragma unroll
        for (int m = 0; m < T; ++m) {
            if (m > 0) {
                const int ko = m - 1;              // < 16 -> no pad term
                const int kn = m - 1 + WIN;
                float a_o = lds1[pbase + ko];
                float b_o = lds2[pbase + ko];
                float a_i = lds1[pbase + kn + 3 * (kn >> 4)];
                float b_i = lds2[pbase + kn + 3 * (kn >> 4)];
                s1 += a_i - a_o;
                s2 += b_i - b_o;
                s11 += fmaf(a_i, a_i, -(a_o * a_o));
                s22 += fmaf(b_i, b_i, -(b_o * b_o));
                s12 += fmaf(a_i, b_i, -(a_o * b_o));
            }
            const float invw = 1.0f / (float)WIN;
            float cov = fmaf(-(s1 * invw), s2, s12);
            float v1v = fmaf(-(s1 * invw), s1, s11);
            float v2v = fmaf(-(s2 * invw), s2, s22);
            float corr = cov * rsqrtf(v1v * v2v);
            if (c0 + m < ncols) orow[c0 + m] = corr;
        }
    }
}

// Reduce: colsum[col] += sum of a 16-row chunk of out (out is L3-hot).
__global__ __launch_bounds__(256)
void swc_reduce(const float* __restrict__ out, float* __restrict__ colsum)
{
    int col = (int)blockIdx.x * 256 + (int)threadIdx.x;
    if (col >= NC) return;
    const int r0 = (int)blockIdx.y * RCHUNK;
    float s = 0.f;
    #pragma unroll
    for (int i = 0; i < RCHUNK; ++i)
        s += out[(size_t)(r0 + i) * NC + col];
    atomicAdd(&colsum[col], s);
}

// Pass 2: out = relu(out - colsum/NROW), flat float4 streaming RMW.
__global__ __launch_bounds__(256)
void swc_pass2(float* __restrict__ out, const float* __restrict__ colsum)
{
    const float inv = 1.0f / (float)NROW;
    int base = (int)blockIdx.x * 2048 + (int)threadIdx.x;   // vec4 units
    #pragma unroll
    for (int v = 0; v < 8; ++v) {
        int i4 = base + v * 256;
        if (i4 < N4) {
            float4 o = ((float4*)out)[i4];
            int idx = i4 << 2;
            int row = (int)((unsigned)idx / (unsigned)NC);
            int col = idx - row * NC;                        // avg depends only on col
            int c1 = col + 1, c2 = col + 2, c3 = col + 3;
            if (c1 >= NC) c1 -= NC;
            if (c2 >= NC) c2 -= NC;
            if (c3 >= NC) c3 -= NC;
            o.x = fmaxf(o.x - colsum[col] * inv, 0.f);
            o.y = fmaxf(o.y - colsum[c1] * inv, 0.f);
            o.z = fmaxf(o.z - colsum[c2] * inv, 0.f);
            o.w = fmaxf(o.w - colsum[c3] * inv, 0.f);
            ((float4*)out)[i4] = o;
        }
    }
}

extern "C" void kernel_launch(void* const* d_in, const int* in_sizes, int n_in,
                              void* d_out, int out_size, void* d_ws, size_t ws_size,
                              hipStream_t stream) {
    const float* x = (const float*)d_in[0];
    float* out = (float*)d_out;
    float* colsum = (float*)d_ws;   // NC floats = ~131 KB scratch (proven available)

    hipMemsetAsync(colsum, 0, NC * sizeof(float), stream);
    swc_pass1<<<dim3(NTILE * RG), dim3(NT1), 0, stream>>>(x, out);
    swc_reduce<<<dim3((NC + 255) / 256, RSPLIT), dim3(256), 0, stream>>>(out, colsum);
    swc_pass2<<<dim3((N4 + 2047) / 2048), dim3(256), 0, stream>>>(out, colsum);
}